// Round 3
// baseline (1535.278 us; speedup 1.0000x reference)
//
#include <hip/hip_runtime.h>

// ---------------- problem constants ----------------
#define B_    32
#define S_    729
#define E_    1152
#define H_    16
#define D_    72
#define M1_   23328      // B_*S_
#define MPAD_ 23424      // 183*128
#define SQ_   736        // Q rows padded (23*32)
#define SK_   768        // K rows padded (6*128)
#define DP_   96         // head dim padded
#define VR_   96         // V^T rows (d padded)
#define SCALE_ 0.11785113019775793f  // 72^-0.5

typedef __attribute__((ext_vector_type(8))) _Float16 f16x8;
typedef __attribute__((ext_vector_type(4))) _Float16 f16x4;
typedef __attribute__((ext_vector_type(4))) float    f32x4;

#define GLDS16(g, l) __builtin_amdgcn_global_load_lds(                      \
    (__attribute__((address_space(1))) void*)(g),                           \
    (__attribute__((address_space(3))) void*)(l), 16, 0, 0)

union H2U { _Float16 h[2]; uint32_t u; };

// ---------------- fp32 -> fp16 convert ----------------
__global__ void cvt_f16(const float4* __restrict__ src, f16x4* __restrict__ dst, int n4) {
  int stride = gridDim.x * blockDim.x;
  for (int i = blockIdx.x * blockDim.x + threadIdx.x; i < n4; i += stride) {
    float4 v = src[i];
    f16x4 o;
    o.x = (_Float16)v.x; o.y = (_Float16)v.y;
    o.z = (_Float16)v.z; o.w = (_Float16)v.w;
    dst[i] = o;
  }
}

// ---------------- 128x128 fp16 MFMA GEMM (m97 structure) ----------------
template<int MODE>
__global__ __launch_bounds__(256)
void gemm_f16(const _Float16* __restrict__ A, const _Float16* __restrict__ W,
              const float* __restrict__ bias,
              _Float16* __restrict__ Qp, _Float16* __restrict__ Kp,
              _Float16* __restrict__ Vtp, float* __restrict__ Cout)
{
  __shared__ _Float16 As[128 * 64];
  __shared__ _Float16 Bs[128 * 64];
  const int tid = threadIdx.x;
  const int l  = tid & 63;
  const int wv = tid >> 6;
  const int lq = l & 15, lk = l >> 4;
  const int m0 = blockIdx.x * 128;
  const int n0 = blockIdx.y * 128;
  const int wm = (wv & 1) * 64, wn = (wv >> 1) * 64;
  const int srow = l >> 3;
  const int scol = (l & 7) * 8;

  f32x4 acc[4][4] = {};

  for (int k0 = 0; k0 < 1152; k0 += 64) {
    #pragma unroll
    for (int q = 0; q < 4; ++q) {
      int chunk = wv * 4 + q;
      int row = chunk * 8 + srow;
      GLDS16(A + (size_t)(m0 + row) * 1152 + k0 + scol, &As[chunk * 512 + l * 8]);
      GLDS16(W + (size_t)(n0 + row) * 1152 + k0 + scol, &Bs[chunk * 512 + l * 8]);
    }
    __syncthreads();
    #pragma unroll
    for (int kk = 0; kk < 64; kk += 32) {
      f16x8 a[4], b[4];
      #pragma unroll
      for (int i = 0; i < 4; ++i)
        a[i] = *(const f16x8*)&As[(wm + 16 * i + lq) * 64 + kk + lk * 8];
      #pragma unroll
      for (int j = 0; j < 4; ++j)
        b[j] = *(const f16x8*)&Bs[(wn + 16 * j + lq) * 64 + kk + lk * 8];
      #pragma unroll
      for (int i = 0; i < 4; ++i)
        #pragma unroll
        for (int j = 0; j < 4; ++j)
          acc[i][j] = __builtin_amdgcn_mfma_f32_16x16x32_f16(a[i], b[j], acc[i][j], 0, 0, 0);
    }
    __syncthreads();
  }

  #pragma unroll
  for (int i = 0; i < 4; ++i) {
    #pragma unroll
    for (int j = 0; j < 4; ++j) {
      int n = n0 + wn + 16 * j + lq;
      float bn = bias[n];
      #pragma unroll
      for (int r = 0; r < 4; ++r) {
        int m = m0 + wm + 16 * i + lk * 4 + r;
        if (m >= M1_) continue;
        float v = acc[i][j][r] + bn;
        if (MODE == 0) {
          unsigned um = (unsigned)m;
          unsigned bq = um / 729u, s = um - bq * 729u;
          unsigned un = (unsigned)n;
          unsigned which = un / 1152u, e = un - which * 1152u;
          unsigned h = e / 72u, d = e - h * 72u;
          unsigned bh = bq * 16u + h;
          if (which == 0) {
            Qp[((size_t)bh * SQ_ + s) * DP_ + d] = (_Float16)(v * SCALE_);
          } else if (which == 1) {
            Kp[((size_t)bh * SK_ + s) * DP_ + d] = (_Float16)v;
          } else {
            Vtp[((size_t)bh * VR_ + d) * 768 + s] = (_Float16)v;
          }
        } else {
          Cout[(size_t)m * 1152 + n] = v;
        }
      }
    }
  }
}

// ---------------- fused attention v3: no K/V LDS staging ----------------
// WG = 512 threads (8 waves), one (qt, bh). Grid: x = qt (fast) -> the 23
// WGs of one head run ~concurrently and share K/V via L2/L3.
// wave: i = wv>>2 (q half, 16 rows), sl = wv&3 (k slice).
// Swapped QK^T: lane (lq,lk) reg (c,r) holds
//   S[q = q0+16i+lq][k = cb*16 + 4*lk + r], cb = 8*(c>>1) + 2*sl + (c&1).
struct AttnSmem {
  float ored[4][32][96];         // 48KB cross-wave O reduce
  uint32_t pexch[8][64][4];      // per-wave P exchange, 8KB
  float redmax[32][4];
  float redsum[32][4];
  float invl[32];
};

__global__ __launch_bounds__(512, 4)
void attn_k(const _Float16* __restrict__ Q, const _Float16* __restrict__ K,
            const _Float16* __restrict__ Vt, float* __restrict__ scores,
            _Float16* __restrict__ AO)
{
  __shared__ AttnSmem sm;
  const int tid = threadIdx.x;
  const int l   = tid & 63;
  const int wv  = tid >> 6;
  const int lq  = l & 15, lk = l >> 4;
  const int i   = wv >> 2;
  const int sl  = wv & 3;
  const int qt  = blockIdx.x;
  const int bh  = blockIdx.y;
  const int q0  = qt * 32;
  const int b   = bh >> 4, h = bh & 15;

  const _Float16* Qb = Q  + (size_t)bh * SQ_ * DP_;
  const _Float16* Kb = K  + (size_t)bh * SK_ * DP_;
  const _Float16* Vb = Vt + (size_t)bh * VR_ * 768;

  // ---- Q fragments (registers) ----
  f16x8 aq[3];
  {
    const _Float16* qp = Qb + (size_t)(q0 + 16 * i + lq) * DP_ + lk * 8;
    aq[0] = *(const f16x8*)(qp);
    aq[1] = *(const f16x8*)(qp + 32);
    aq[2] = *(const f16x8*)(qp + 64);
  }

  // ---- QK^T, K fragments straight from global (L2-resident) ----
  f32x4 sacc[12] = {};
  #pragma unroll
  for (int c = 0; c < 12; ++c) {
    int cb = 8 * (c >> 1) + 2 * sl + (c & 1);
    const _Float16* kp = Kb + (size_t)(cb * 16 + lq) * DP_ + lk * 8;
    f16x8 k0 = *(const f16x8*)(kp);
    f16x8 k1 = *(const f16x8*)(kp + 32);
    f16x8 k2 = *(const f16x8*)(kp + 64);
    sacc[c] = __builtin_amdgcn_mfma_f32_16x16x32_f16(k0, aq[0], sacc[c], 0, 0, 0);
    sacc[c] = __builtin_amdgcn_mfma_f32_16x16x32_f16(k1, aq[1], sacc[c], 0, 0, 0);
    sacc[c] = __builtin_amdgcn_mfma_f32_16x16x32_f16(k2, aq[2], sacc[c], 0, 0, 0);
  }

  // ---- mask invalid k (cb >= 45 only possible at c=10,11) ----
  #pragma unroll
  for (int c = 10; c < 12; ++c) {
    int kbase = (40 + 2 * sl + (c & 1)) * 16 + 4 * lk;
    #pragma unroll
    for (int r = 0; r < 4; ++r)
      if (kbase + r > 728) sacc[c][r] = -1e30f;
  }

  // ---- row max ----
  float m = -1e30f;
  #pragma unroll
  for (int c = 0; c < 12; ++c)
    #pragma unroll
    for (int r = 0; r < 4; ++r) m = fmaxf(m, sacc[c][r]);
  m = fmaxf(m, __shfl_xor(m, 16));
  m = fmaxf(m, __shfl_xor(m, 32));
  if (lk == 0) sm.redmax[16 * i + lq][sl] = m;
  asm volatile("s_waitcnt lgkmcnt(0)" ::: "memory");
  __builtin_amdgcn_s_barrier();
  float gm;
  { const float* rp = sm.redmax[16 * i + lq];
    gm = fmaxf(fmaxf(rp[0], rp[1]), fmaxf(rp[2], rp[3])); }

  // ---- exp + row sum ----
  float sum = 0.f;
  #pragma unroll
  for (int c = 0; c < 12; ++c)
    #pragma unroll
    for (int r = 0; r < 4; ++r) {
      float e = __expf(sacc[c][r] - gm);
      sacc[c][r] = e;
      sum += e;
    }
  sum += __shfl_xor(sum, 16);
  sum += __shfl_xor(sum, 32);
  if (lk == 0) sm.redsum[16 * i + lq][sl] = sum;
  asm volatile("s_waitcnt lgkmcnt(0)" ::: "memory");
  __builtin_amdgcn_s_barrier();
  float inv;
  { const float* rp = sm.redsum[16 * i + lq];
    inv = 1.0f / (rp[0] + rp[1] + rp[2] + rp[3]); }
  if (lk == 0 && sl == 0) sm.invl[16 * i + lq] = inv;

  // ---- normalized scores store (f32x4, contiguous) ----
  {
    const int q = q0 + 16 * i + lq;
    if (q < S_) {
      float* sc = scores + (size_t)bh * S_ * S_ + (size_t)q * S_;
      #pragma unroll
      for (int c = 0; c < 12; ++c) {
        int k0 = (8 * (c >> 1) + 2 * sl + (c & 1)) * 16 + 4 * lk;
        f32x4 v = sacc[c] * inv;
        if (k0 + 3 <= 728)      *(f32x4*)(sc + k0) = v;
        else if (k0 == 728)     sc[728] = v[0];
      }
    }
  }

  // ---- pack P (unnormalized e) to fp16 pairs ----
  uint32_t pk[12][2];
  #pragma unroll
  for (int c = 0; c < 12; ++c) {
    H2U a0, a1;
    a0.h[0] = (_Float16)sacc[c][0]; a0.h[1] = (_Float16)sacc[c][1];
    a1.h[0] = (_Float16)sacc[c][2]; a1.h[1] = (_Float16)sacc[c][3];
    pk[c][0] = a0.u; pk[c][1] = a1.u;
  }

  // ---- PV: V fragments straight from global; P via in-wave LDS exchange ----
  f32x4 oacc[6] = {};
  const int srcA = lq + 16 * (2 * (lk & 1));
  const int srcB = srcA + 16;
  #pragma unroll
  for (int t = 0; t < 6; ++t) {
    uint4 w = make_uint4(pk[2 * t][0], pk[2 * t][1], pk[2 * t + 1][0], pk[2 * t + 1][1]);
    *(uint4*)&sm.pexch[wv][l][0] = w;
    asm volatile("s_waitcnt lgkmcnt(0)" ::: "memory");
    __builtin_amdgcn_sched_barrier(0);
    uint2 dA = *(const uint2*)((const char*)&sm.pexch[wv][srcA][0] + (lk >> 1) * 8);
    uint2 dB = *(const uint2*)((const char*)&sm.pexch[wv][srcB][0] + (lk >> 1) * 8);
    uint4 pad4 = make_uint4(dA.x, dA.y, dB.x, dB.y);
    f16x8 pa = __builtin_bit_cast(f16x8, pad4);

    #pragma unroll
    for (int db = 0; db < 6; ++db) {
      const _Float16* vp = Vb + (size_t)(db * 16 + lq) * 768 + t * 128 + (4 * sl + lk) * 8;
      f16x8 bv = *(const f16x8*)(vp);
      oacc[db] = __builtin_amdgcn_mfma_f32_16x16x32_f16(pa, bv, oacc[db], 0, 0, 0);
    }
  }

  // ---- cross-wave O reduce ----
  #pragma unroll
  for (int db = 0; db < 6; ++db)
    #pragma unroll
    for (int r = 0; r < 4; ++r)
      sm.ored[sl][16 * i + lk * 4 + r][db * 16 + lq] = oacc[db][r];
  asm volatile("s_waitcnt lgkmcnt(0)" ::: "memory");
  __builtin_amdgcn_s_barrier();

  {
    int qq = tid >> 4, dc = tid & 15;
    int qglob = q0 + qq;
    if (dc < 12 && qglob < S_) {
      int d0 = dc * 6;
      float iv = sm.invl[qq];
      _Float16* ap = AO + ((size_t)(b * S_ + qglob)) * E_ + h * D_ + d0;
      #pragma unroll
      for (int e = 0; e < 6; ++e) {
        float v = sm.ored[0][qq][d0 + e] + sm.ored[1][qq][d0 + e]
                + sm.ored[2][qq][d0 + e] + sm.ored[3][qq][d0 + e];
        ap[e] = (_Float16)(v * iv);
      }
    }
  }
}

// ---------------- host launch ----------------
extern "C" void kernel_launch(void* const* d_in, const int* in_sizes, int n_in,
                              void* d_out, int out_size, void* d_ws, size_t ws_size,
                              hipStream_t stream)
{
  const float* hidden = (const float*)d_in[0];
  const float* qkv_w  = (const float*)d_in[1];
  const float* qkv_b  = (const float*)d_in[2];
  const float* out_w  = (const float*)d_in[3];
  const float* out_b  = (const float*)d_in[4];
  float* out    = (float*)d_out;
  float* scores = out + (size_t)M1_ * E_;

  char* ws = (char*)d_ws;
  const size_t szA1 = (size_t)MPAD_ * 1152 * 2;
  const size_t szWq = (size_t)3456 * 1152 * 2;
  const size_t szWo = (size_t)1152 * 1152 * 2;
  const size_t szQ  = (size_t)512 * SQ_ * DP_ * 2;
  const size_t szK  = (size_t)512 * SK_ * DP_ * 2;
  const size_t szV  = (size_t)512 * VR_ * 768 * 2;
  const size_t offA1 = 0;
  const size_t offWq = offA1 + szA1;
  const size_t offWo = offWq + szWq;
  const size_t offQ  = offWo + szWo;
  const size_t offK  = offQ  + szQ;
  const size_t offVt = offK  + szK;
  const size_t need  = offVt + szV;          // ~275 MiB
  if (ws_size < need) return;

  _Float16* A1  = (_Float16*)(ws + offA1);
  _Float16* Wq  = (_Float16*)(ws + offWq);
  _Float16* Wo  = (_Float16*)(ws + offWo);
  _Float16* Qp  = (_Float16*)(ws + offQ);
  _Float16* Kp  = (_Float16*)(ws + offK);
  _Float16* Vtp = (_Float16*)(ws + offVt);
  _Float16* AO  = A1;   // reuse A1 (dead after GEMM1)

  // Only K's d-pad must be zero (Q-pad * 0 = 0; V k-pad nullified by P=0).
  hipMemsetAsync(Kp, 0, szK, stream);

  cvt_f16<<<26244, 256, 0, stream>>>((const float4*)hidden, (f16x4*)A1, (M1_ * E_) / 4);
  cvt_f16<<<3888,  256, 0, stream>>>((const float4*)qkv_w,  (f16x4*)Wq, (3456 * 1152) / 4);
  cvt_f16<<<1296,  256, 0, stream>>>((const float4*)out_w,  (f16x4*)Wo, (1152 * 1152) / 4);

  gemm_f16<0><<<dim3(183, 27), 256, 0, stream>>>(A1, Wq, qkv_b, Qp, Kp, Vtp, nullptr);
  attn_k<<<dim3(23, 512), 512, 0, stream>>>(Qp, Kp, Vtp, scores, AO);
  gemm_f16<1><<<dim3(183, 9), 256, 0, stream>>>(AO, Wo, out_b, nullptr, nullptr, nullptr, out);
}

// Round 5
// 1174.334 us; speedup vs baseline: 1.3074x; 1.3074x over previous
//
#include <hip/hip_runtime.h>

// ---------------- problem constants ----------------
#define B_    32
#define S_    729
#define E_    1152
#define H_    16
#define D_    72
#define M1_   23328      // B_*S_
#define MPAD_ 23424      // 183*128
#define SQ_   736        // Q rows padded (23*32)
#define SK_   768        // K rows padded (6*128)
#define DP_   96         // head dim padded
#define VR_   96         // V^T rows (d padded)
#define SCALE_ 0.11785113019775793f  // 72^-0.5

typedef __attribute__((ext_vector_type(8))) _Float16 f16x8;
typedef __attribute__((ext_vector_type(4))) _Float16 f16x4;
typedef __attribute__((ext_vector_type(4))) float    f32x4;

#define GLDS16(g, l) __builtin_amdgcn_global_load_lds(                      \
    (__attribute__((address_space(1))) void*)(g),                           \
    (__attribute__((address_space(3))) void*)(l), 16, 0, 0)

union H2U { _Float16 h[2]; uint32_t u; };

// ---------------- fp32 -> fp16 convert ----------------
__global__ void cvt_f16(const float4* __restrict__ src, f16x4* __restrict__ dst, int n4) {
  int stride = gridDim.x * blockDim.x;
  for (int i = blockIdx.x * blockDim.x + threadIdx.x; i < n4; i += stride) {
    float4 v = src[i];
    f16x4 o;
    o.x = (_Float16)v.x; o.y = (_Float16)v.y;
    o.z = (_Float16)v.z; o.w = (_Float16)v.w;
    dst[i] = o;
  }
}

// ---------------- 128x128 fp16 MFMA GEMM (m97 structure) ----------------
template<int MODE>
__global__ __launch_bounds__(256)
void gemm_f16(const _Float16* __restrict__ A, const _Float16* __restrict__ W,
              const float* __restrict__ bias,
              _Float16* __restrict__ Qp, _Float16* __restrict__ Kp,
              _Float16* __restrict__ Vtp, float* __restrict__ Cout)
{
  __shared__ _Float16 As[128 * 64];
  __shared__ _Float16 Bs[128 * 64];
  const int tid = threadIdx.x;
  const int l  = tid & 63;
  const int wv = tid >> 6;
  const int lq = l & 15, lk = l >> 4;
  const int m0 = blockIdx.x * 128;
  const int n0 = blockIdx.y * 128;
  const int wm = (wv & 1) * 64, wn = (wv >> 1) * 64;
  const int srow = l >> 3;
  const int scol = (l & 7) * 8;

  f32x4 acc[4][4] = {};

  for (int k0 = 0; k0 < 1152; k0 += 64) {
    #pragma unroll
    for (int q = 0; q < 4; ++q) {
      int chunk = wv * 4 + q;
      int row = chunk * 8 + srow;
      GLDS16(A + (size_t)(m0 + row) * 1152 + k0 + scol, &As[chunk * 512 + l * 8]);
      GLDS16(W + (size_t)(n0 + row) * 1152 + k0 + scol, &Bs[chunk * 512 + l * 8]);
    }
    __syncthreads();
    #pragma unroll
    for (int kk = 0; kk < 64; kk += 32) {
      f16x8 a[4], b[4];
      #pragma unroll
      for (int i = 0; i < 4; ++i)
        a[i] = *(const f16x8*)&As[(wm + 16 * i + lq) * 64 + kk + lk * 8];
      #pragma unroll
      for (int j = 0; j < 4; ++j)
        b[j] = *(const f16x8*)&Bs[(wn + 16 * j + lq) * 64 + kk + lk * 8];
      #pragma unroll
      for (int i = 0; i < 4; ++i)
        #pragma unroll
        for (int j = 0; j < 4; ++j)
          acc[i][j] = __builtin_amdgcn_mfma_f32_16x16x32_f16(a[i], b[j], acc[i][j], 0, 0, 0);
    }
    __syncthreads();
  }

  #pragma unroll
  for (int i = 0; i < 4; ++i) {
    #pragma unroll
    for (int j = 0; j < 4; ++j) {
      int n = n0 + wn + 16 * j + lq;
      float bn = bias[n];
      #pragma unroll
      for (int r = 0; r < 4; ++r) {
        int m = m0 + wm + 16 * i + lk * 4 + r;
        if (m >= M1_) continue;
        float v = acc[i][j][r] + bn;
        if (MODE == 0) {
          unsigned um = (unsigned)m;
          unsigned bq = um / 729u, s = um - bq * 729u;
          unsigned un = (unsigned)n;
          unsigned which = un / 1152u, e = un - which * 1152u;
          unsigned h = e / 72u, d = e - h * 72u;
          unsigned bh = bq * 16u + h;
          if (which == 0) {
            Qp[((size_t)bh * SQ_ + s) * DP_ + d] = (_Float16)(v * SCALE_);
          } else if (which == 1) {
            Kp[((size_t)bh * SK_ + s) * DP_ + d] = (_Float16)v;
          } else {
            Vtp[((size_t)bh * VR_ + d) * 768 + s] = (_Float16)v;
          }
        } else {
          Cout[(size_t)m * 1152 + n] = v;
        }
      }
    }
  }
}

// ---------------- fused attention v4b ----------------
// 512 thr (8 waves) per WG; one (bh, 32-q tile). XCD-pinned: all 23 q-tiles
// of a head on one XCD (its L2 caches that head's K/V once).
// 12-tile async pipeline (6 K + 6 V) through 2 LDS buffers, counted vmcnt(3).
// Swapped QK^T: lane (lq,lk) reg (c,r): S[q=q0+16i+lq][k=cb*16+4lk+r],
// cb = 8*(c>>1) + 2*sl + (c&1).  Scores stored at kernel end from fp16 pk.
struct AttnSmem {
  union {
    char  stage[2][24576];       // K tile [128][192B] / V tile [96][256B]
    float ored[4][32][96];       // 48KB O-reduce (after PV)
  };
  uint32_t pexch[8][64][4];      // per-wave P exchange, 8KB
  float redmax[32][4];
  float redsum[32][4];
  float invl[32];
};

__global__ __launch_bounds__(512, 4)
void attn_k(const _Float16* __restrict__ Q, const _Float16* __restrict__ K,
            const _Float16* __restrict__ Vt, float* __restrict__ scores,
            _Float16* __restrict__ AO)
{
  __shared__ AttnSmem sm;
  const int tid = threadIdx.x;
  const int l   = tid & 63;
  const int wv  = tid >> 6;
  const int lq  = l & 15, lk = l >> 4;
  const int i   = wv >> 2;
  const int sl  = wv & 3;
  // XCD-pinned decode: phys block p -> xcd = p%8; head bh = hl*8+xcd
  const int p    = blockIdx.x;
  const int xcd  = p & 7;
  const int slot = p >> 3;
  const int hl   = slot / 23;
  const int qt   = slot - hl * 23;
  const int bh   = hl * 8 + xcd;
  const int q0   = qt * 32;
  const int b    = bh >> 4, h = bh & 15;

  const _Float16* Qb = Q  + (size_t)bh * SQ_ * DP_;
  const _Float16* Kb = K  + (size_t)bh * SK_ * DP_;
  const _Float16* Vb = Vt + (size_t)bh * VR_ * 768;

  // tiles 0..5 = K tiles, 6..11 = V tiles; buffer = idx&1
  auto stage = [&](int idx) {
    char* buf = sm.stage[idx & 1];
    if (idx < 6) {
      #pragma unroll
      for (int it = 0; it < 3; ++it) {
        int s = it * 512 + tid;                 // 1536 chunks of 16B
        int row = s / 12, cp = s - row * 12;
        int cc = (cp < 8) ? (cp ^ (row & 7)) : (8 + ((cp & 3) ^ ((row >> 1) & 3)));
        GLDS16(Kb + (size_t)(idx * 128 + row) * DP_ + cc * 8, buf + s * 16);
      }
    } else {
      #pragma unroll
      for (int it = 0; it < 3; ++it) {
        int s = it * 512 + tid;
        int row = s >> 4, cp = s & 15;
        int cc = cp ^ (row & 15);
        GLDS16(Vb + (size_t)row * 768 + (idx - 6) * 128 + cc * 8, buf + s * 16);
      }
    }
  };

  // ---- prologue: 2 tiles in flight + Q frags ----
  stage(0);
  stage(1);
  f16x8 aq[3];
  {
    const _Float16* qp = Qb + (size_t)(q0 + 16 * i + lq) * DP_ + lk * 8;
    aq[0] = *(const f16x8*)(qp);
    aq[1] = *(const f16x8*)(qp + 32);
    aq[2] = *(const f16x8*)(qp + 64);
  }
  asm volatile("s_waitcnt vmcnt(0)" ::: "memory");
  __builtin_amdgcn_s_barrier();

  // ---- QK^T over 6 staged K-tiles ----
  f32x4 sacc[12] = {};
  #pragma unroll
  for (int t = 0; t < 6; ++t) {
    asm volatile("s_waitcnt vmcnt(3)" ::: "memory");
    __builtin_amdgcn_s_barrier();
    const char* bufp = sm.stage[t & 1];
    #pragma unroll
    for (int lcb = 0; lcb < 2; ++lcb) {
      int row = (2 * sl + lcb) * 16 + lq;
      #pragma unroll
      for (int t3 = 0; t3 < 3; ++t3) {
        int cc = 4 * t3 + lk;
        int cp = (cc < 8) ? (cc ^ (row & 7)) : (8 + ((cc & 3) ^ ((row >> 1) & 3)));
        f16x8 ka = *(const f16x8*)(bufp + row * 192 + cp * 16);
        sacc[2 * t + lcb] = __builtin_amdgcn_mfma_f32_16x16x32_f16(ka, aq[t3], sacc[2 * t + lcb], 0, 0, 0);
      }
    }
    asm volatile("s_waitcnt lgkmcnt(0)" ::: "memory");
    __builtin_amdgcn_s_barrier();
    stage(t + 2);                 // t+2: K2..K5 then V0,V1
  }

  // ---- mask invalid k (cb >= 45 only at c=10,11) ----
  #pragma unroll
  for (int c = 10; c < 12; ++c) {
    int kbase = (40 + 2 * sl + (c & 1)) * 16 + 4 * lk;
    #pragma unroll
    for (int r = 0; r < 4; ++r)
      if (kbase + r > 728) sacc[c][r] = -1e30f;
  }

  // ---- row max (V0/V1 loads in flight underneath) ----
  float m = -1e30f;
  #pragma unroll
  for (int c = 0; c < 12; ++c)
    #pragma unroll
    for (int r = 0; r < 4; ++r) m = fmaxf(m, sacc[c][r]);
  m = fmaxf(m, __shfl_xor(m, 16));
  m = fmaxf(m, __shfl_xor(m, 32));
  if (lk == 0) sm.redmax[16 * i + lq][sl] = m;
  asm volatile("s_waitcnt lgkmcnt(0)" ::: "memory");
  __builtin_amdgcn_s_barrier();
  float gm;
  { const float* rp = sm.redmax[16 * i + lq];
    gm = fmaxf(fmaxf(rp[0], rp[1]), fmaxf(rp[2], rp[3])); }

  // ---- exp + row sum ----
  float sum = 0.f;
  #pragma unroll
  for (int c = 0; c < 12; ++c)
    #pragma unroll
    for (int r = 0; r < 4; ++r) {
      float e = __expf(sacc[c][r] - gm);
      sacc[c][r] = e;
      sum += e;
    }
  sum += __shfl_xor(sum, 16);
  sum += __shfl_xor(sum, 32);
  if (lk == 0) sm.redsum[16 * i + lq][sl] = sum;
  asm volatile("s_waitcnt lgkmcnt(0)" ::: "memory");
  __builtin_amdgcn_s_barrier();
  float inv;
  { const float* rp = sm.redsum[16 * i + lq];
    inv = 1.0f / (rp[0] + rp[1] + rp[2] + rp[3]); }
  if (lk == 0 && sl == 0) sm.invl[16 * i + lq] = inv;

  // ---- pack P (unnormalized e) to fp16 pairs; sacc dead after ----
  uint32_t pk[12][2];
  #pragma unroll
  for (int c = 0; c < 12; ++c) {
    H2U a0, a1;
    a0.h[0] = (_Float16)sacc[c][0]; a0.h[1] = (_Float16)sacc[c][1];
    a1.h[0] = (_Float16)sacc[c][2]; a1.h[1] = (_Float16)sacc[c][3];
    pk[c][0] = a0.u; pk[c][1] = a1.u;
  }

  // ---- PV over 6 staged V-tiles ----
  f32x4 oacc[6] = {};
  const int srcA = lq + 16 * (2 * (lk & 1));
  const int srcB = srcA + 16;
  #pragma unroll
  for (int v = 0; v < 6; ++v) {
    if (v < 5) { asm volatile("s_waitcnt vmcnt(3)" ::: "memory"); }
    else       { asm volatile("s_waitcnt vmcnt(0)" ::: "memory"); }
    __builtin_amdgcn_s_barrier();
    // in-wave P exchange (wave-private)
    uint4 w = make_uint4(pk[2 * v][0], pk[2 * v][1], pk[2 * v + 1][0], pk[2 * v + 1][1]);
    *(uint4*)&sm.pexch[wv][l][0] = w;
    asm volatile("s_waitcnt lgkmcnt(0)" ::: "memory");
    __builtin_amdgcn_sched_barrier(0);
    uint2 dA = *(const uint2*)((const char*)&sm.pexch[wv][srcA][0] + (lk >> 1) * 8);
    uint2 dB = *(const uint2*)((const char*)&sm.pexch[wv][srcB][0] + (lk >> 1) * 8);
    uint4 pad4 = make_uint4(dA.x, dA.y, dB.x, dB.y);
    f16x8 pa = __builtin_bit_cast(f16x8, pad4);

    const char* bufp = sm.stage[v & 1];
    #pragma unroll
    for (int db = 0; db < 6; ++db) {
      int row = db * 16 + lq;
      int cc = 4 * sl + lk;
      int cp = cc ^ (row & 15);
      f16x8 bv = *(const f16x8*)(bufp + row * 256 + cp * 16);
      oacc[db] = __builtin_amdgcn_mfma_f32_16x16x32_f16(pa, bv, oacc[db], 0, 0, 0);
    }
    asm volatile("s_waitcnt lgkmcnt(0)" ::: "memory");
    __builtin_amdgcn_s_barrier();
    if (v < 4) stage(v + 8);      // V2..V5
  }

  // ---- cross-wave O reduce (ored unions with stage; XOR-swizzled cols) ----
  // All waves' LDS reads drained (lgkmcnt(0)+barrier above) before overwrite.
  #pragma unroll
  for (int db = 0; db < 6; ++db)
    #pragma unroll
    for (int r = 0; r < 4; ++r) {
      int row = 16 * i + lk * 4 + r;
      sm.ored[sl][row][(db * 16 + lq) ^ (row & 12)] = oacc[db][r];
    }

  // ---- normalized scores store (from fp16 pk; after vmcnt window) ----
  {
    const int q = q0 + 16 * i + lq;
    if (q < S_) {
      float* sc = scores + (size_t)bh * S_ * S_ + (size_t)q * S_;
      #pragma unroll
      for (int c = 0; c < 12; ++c) {
        int k0 = (8 * (c >> 1) + 2 * sl + (c & 1)) * 16 + 4 * lk;
        H2U u0, u1; u0.u = pk[c][0]; u1.u = pk[c][1];
        f32x4 vv;
        vv[0] = (float)u0.h[0] * inv; vv[1] = (float)u0.h[1] * inv;
        vv[2] = (float)u1.h[0] * inv; vv[3] = (float)u1.h[1] * inv;
        if (k0 + 3 <= 728)  *(f32x4*)(sc + k0) = vv;
        else if (k0 == 728) sc[728] = vv[0];
      }
    }
  }

  asm volatile("s_waitcnt lgkmcnt(0)" ::: "memory");
  __builtin_amdgcn_s_barrier();

  // ---- final AO write ----
  {
    int qq = tid >> 4, dc = tid & 15;
    int qglob = q0 + qq;
    if (dc < 12 && qglob < S_) {
      int d0 = dc * 6;
      float iv = sm.invl[qq];
      _Float16* ap = AO + ((size_t)(b * S_ + qglob)) * E_ + h * D_ + d0;
      #pragma unroll
      for (int e = 0; e < 6; ++e) {
        int col = (d0 + e) ^ (qq & 12);
        float v = sm.ored[0][qq][col] + sm.ored[1][qq][col]
                + sm.ored[2][qq][col] + sm.ored[3][qq][col];
        ap[e] = (_Float16)(v * iv);
      }
    }
  }
}

// ---------------- host launch ----------------
extern "C" void kernel_launch(void* const* d_in, const int* in_sizes, int n_in,
                              void* d_out, int out_size, void* d_ws, size_t ws_size,
                              hipStream_t stream)
{
  const float* hidden = (const float*)d_in[0];
  const float* qkv_w  = (const float*)d_in[1];
  const float* qkv_b  = (const float*)d_in[2];
  const float* out_w  = (const float*)d_in[3];
  const float* out_b  = (const float*)d_in[4];
  float* out    = (float*)d_out;
  float* scores = out + (size_t)M1_ * E_;

  char* ws = (char*)d_ws;
  const size_t szA1 = (size_t)MPAD_ * 1152 * 2;
  const size_t szWq = (size_t)3456 * 1152 * 2;
  const size_t szWo = (size_t)1152 * 1152 * 2;
  const size_t szQ  = (size_t)512 * SQ_ * DP_ * 2;
  const size_t szK  = (size_t)512 * SK_ * DP_ * 2;
  const size_t szV  = (size_t)512 * VR_ * 768 * 2;
  const size_t offA1 = 0;
  const size_t offWq = offA1 + szA1;
  const size_t offWo = offWq + szWq;
  const size_t offQ  = offWo + szWo;
  const size_t offK  = offQ  + szQ;
  const size_t offVt = offK  + szK;
  const size_t need  = offVt + szV;          // ~275 MiB
  if (ws_size < need) return;

  _Float16* A1  = (_Float16*)(ws + offA1);
  _Float16* Wq  = (_Float16*)(ws + offWq);
  _Float16* Wo  = (_Float16*)(ws + offWo);
  _Float16* Qp  = (_Float16*)(ws + offQ);
  _Float16* Kp  = (_Float16*)(ws + offK);
  _Float16* Vtp = (_Float16*)(ws + offVt);
  _Float16* AO  = A1;   // reuse A1 (dead after GEMM1)

  // Pads MUST be zero: garbage (esp. NaN bit patterns) in V^T k-pad would
  // contaminate PV via 0*NaN=NaN. Deterministic: memset all padded bufs.
  hipMemsetAsync(Qp,  0, szQ, stream);
  hipMemsetAsync(Kp,  0, szK, stream);
  hipMemsetAsync(Vtp, 0, szV, stream);

  cvt_f16<<<26244, 256, 0, stream>>>((const float4*)hidden, (f16x4*)A1, (M1_ * E_) / 4);
  cvt_f16<<<3888,  256, 0, stream>>>((const float4*)qkv_w,  (f16x4*)Wq, (3456 * 1152) / 4);
  cvt_f16<<<1296,  256, 0, stream>>>((const float4*)out_w,  (f16x4*)Wo, (1152 * 1152) / 4);

  gemm_f16<0><<<dim3(183, 27), 256, 0, stream>>>(A1, Wq, qkv_b, Qp, Kp, Vtp, nullptr);
  attn_k<<<11776, 512, 0, stream>>>(Qp, Kp, Vtp, scores, AO);
  gemm_f16<1><<<dim3(183, 9), 256, 0, stream>>>(AO, Wo, out_b, nullptr, nullptr, nullptr, out);
}